// Round 1
// baseline (63.947 us; speedup 1.0000x reference)
//
#include <hip/hip_runtime.h>

#define NQ     32768          // 512 rays * 64 samples
#define NP     4096           // particles
#define KNN    32
#define BLKQ   64             // queries per block (one per lane of wave 0)
#define NWAVE  8              // waves per block, each owns a particle chunk
#define CHUNK  (NP / NWAVE)   // 512 particles per wave
#define THREADS (BLKQ * NWAVE)

__global__ __launch_bounds__(THREADS) void knn_smooth_kernel(
    const float* __restrict__ rp,   // [NQ,3] flattened queries
    const float* __restrict__ pc,   // [NP,3] particles
    float* __restrict__ out)        // [NQ,4]
{
    __shared__ float4 sp[NP];              // 64 KB, particles padded to float4
    __shared__ float  red[5][NWAVE][BLKQ]; // 10 KB, cross-wave partials (also rare-path scratch)
    __shared__ int    sflag[BLKQ];
    __shared__ int    scnt;
    __shared__ float  ord[KNN][4];         // rank-ordered rare-path accumulation (deterministic)

    const int tid  = threadIdx.x;
    const int lane = tid & 63;
    const int wv   = tid >> 6;
    const int blk  = blockIdx.x;

    // ---- stage particles into LDS (coalesced reads) ----
    float* spf = (float*)sp;
    for (int i = tid; i < NP * 3; i += THREADS) {
        int p = i / 3;
        int c = i - 3 * p;
        spf[4 * p + c] = pc[i];
    }
    __syncthreads();

    const int   q  = blk * BLKQ + lane;
    const float qx = rp[3 * q + 0];
    const float qy = rp[3 * q + 1];
    const float qz = rp[3 * q + 2];

    const float R2 = 0.1f * 0.1f;

    float sw = 0.f, swx = 0.f, swy = 0.f, swz = 0.f;
    int   cnt = 0;

    // ---- main loop: this wave's particle chunk, wave-uniform LDS broadcast ----
    const int p0 = wv * CHUNK;
    #pragma unroll 4
    for (int p = p0; p < p0 + CHUNK; ++p) {
        float4 pp = sp[p];
        float dx = pp.x - qx, dy = pp.y - qy, dz = pp.z - qz;
        float d2 = fmaf(dx, dx, fmaf(dy, dy, dz * dz));
        if (d2 <= R2) {                       // ~23% of iterations have any lane active
            float d = sqrtf(d2);
            float w = fmaxf(fmaf(d2 * d, -1000.f, 1.f), 0.f);  // 1 - (d/0.1)^3
            cnt += 1;
            sw  += w;
            swx = fmaf(w, pp.x, swx);
            swy = fmaf(w, pp.y, swy);
            swz = fmaf(w, pp.z, swz);
        }
    }

    red[0][wv][lane] = sw;
    red[1][wv][lane] = swx;
    red[2][wv][lane] = swy;
    red[3][wv][lane] = swz;
    red[4][wv][lane] = (float)cnt;
    __syncthreads();

    // ---- cross-wave reduce + fast-path output (count <= K) ----
    if (tid < BLKQ) {
        float tsw = 0.f, tswx = 0.f, tswy = 0.f, tswz = 0.f;
        int   tc = 0;
        #pragma unroll
        for (int w = 0; w < NWAVE; ++w) {
            tsw  += red[0][w][tid];
            tswx += red[1][w][tid];
            tswy += red[2][w][tid];
            tswz += red[3][w][tid];
            tc   += (int)red[4][w][tid];
        }
        int flagged = (tc > KNN) ? 1 : 0;
        sflag[tid] = flagged;
        if (!flagged) {
            // masked slots: neighbor == (0,0,0) -> nn_d = ||q|| -> weight w0
            float nq2 = fmaf(qx, qx, fmaf(qy, qy, qz * qz));
            float nq  = sqrtf(nq2);
            float w0  = fmaxf(fmaf(nq2 * nq, -1000.f, 1.f), 0.f);
            float dens = tsw + (float)(KNN - tc) * w0;
            float inv  = 1.f / (dens + 1e-12f);
            float4 o;
            o.x = tswx * inv; o.y = tswy * inv; o.z = tswz * inv; o.w = dens;
            ((float4*)out)[q] = o;
        }
    }
    __syncthreads();

    // ---- rare path: count > K (expected ~1e-4 of queries) -> exact top-K ----
    float* sd2 = &red[0][0][0];       // capacity 1024 (red holds 2560 floats)
    int*   sid = (int*)(sd2 + 1024);  // capacity 1024
    for (int f = 0; f < BLKQ; ++f) {
        if (!sflag[f]) continue;      // block-uniform branch
        if (tid == 0) scnt = 0;
        __syncthreads();
        const int   fq = blk * BLKQ + f;
        const float fx = rp[3 * fq + 0];
        const float fy = rp[3 * fq + 1];
        const float fz = rp[3 * fq + 2];
        // collect all within-radius (d2, idx) entries
        for (int p = tid; p < NP; p += THREADS) {
            float4 pp = sp[p];
            float dx = pp.x - fx, dy = pp.y - fy, dz = pp.z - fz;
            float d2 = fmaf(dx, dx, fmaf(dy, dy, dz * dz));
            if (d2 <= R2) {
                int pos = atomicAdd(&scnt, 1);
                if (pos < 1024) { sd2[pos] = d2; sid[pos] = p; }
            }
        }
        __syncthreads();
        const int ne = (scnt < 1024) ? scnt : 1024;
        // exact rank per entry: lexicographic (d2, idx) matches lax.top_k stable ties
        for (int e = tid; e < ne; e += THREADS) {
            float myd = sd2[e];
            int   myi = sid[e];
            int rank = 0;
            for (int j = 0; j < ne; ++j) {
                float dj = sd2[j];
                int   ij = sid[j];
                rank += (dj < myd || (dj == myd && ij < myi)) ? 1 : 0;
            }
            if (rank < KNN) {   // exactly K entries get ranks 0..K-1
                float4 pp = sp[myi];
                float d = sqrtf(myd);
                float w = fmaxf(fmaf(myd * d, -1000.f, 1.f), 0.f);
                ord[rank][0] = w;
                ord[rank][1] = w * pp.x;
                ord[rank][2] = w * pp.y;
                ord[rank][3] = w * pp.z;
            }
        }
        __syncthreads();
        if (tid == 0) {
            float t0 = 0.f, t1 = 0.f, t2 = 0.f, t3 = 0.f;
            #pragma unroll
            for (int r = 0; r < KNN; ++r) {
                t0 += ord[r][0]; t1 += ord[r][1]; t2 += ord[r][2]; t3 += ord[r][3];
            }
            float inv = 1.f / (t0 + 1e-12f);   // m = 0 here: all K slots kept
            float4 o;
            o.x = t1 * inv; o.y = t2 * inv; o.z = t3 * inv; o.w = t0;
            ((float4*)out)[fq] = o;
        }
        __syncthreads();
    }
}

extern "C" void kernel_launch(void* const* d_in, const int* in_sizes, int n_in,
                              void* d_out, int out_size, void* d_ws, size_t ws_size,
                              hipStream_t stream) {
    const float* rp  = (const float*)d_in[0];   // ray_particles [512,64,3]
    const float* pc  = (const float*)d_in[1];   // particles    [4096,3]
    float*       out = (float*)d_out;           // [512,64,4]
    knn_smooth_kernel<<<NQ / BLKQ, THREADS, 0, stream>>>(rp, pc, out);
}